// Round 1
// baseline (441.270 us; speedup 1.0000x reference)
//
#include <hip/hip_runtime.h>

#define DEV __device__ __forceinline__

constexpr int N = 50000;
constexpr int E = 500000;
constexpr int D = 128;
constexpr int DFF = 256;

typedef __attribute__((ext_vector_type(8))) short bfrag8;
typedef __attribute__((ext_vector_type(4))) float f32x4;

// ---------- helpers ----------
DEV unsigned short f2b(float f) {
    unsigned u = __float_as_uint(f);
    unsigned r = (u + 0x7FFFu + ((u >> 16) & 1u)) >> 16;
    return (unsigned short)r;
}
DEV unsigned pack2(float a, float b) {
    return (unsigned)f2b(a) | ((unsigned)f2b(b) << 16);
}
DEV float2 ld2b(const unsigned short* p) {
    unsigned u = *(const unsigned*)p;
    float2 r;
    r.x = __uint_as_float(u << 16);
    r.y = __uint_as_float(u & 0xFFFF0000u);
    return r;
}

// ---------- workspace layout (bytes) ----------
constexpr size_t AL(size_t x) { return (x + 511) & ~(size_t)511; }
constexpr size_t OFF_COUNTS = 0;                                  // N int
constexpr size_t OFF_CURSORS = AL(OFF_COUNTS + (size_t)N * 4);    // N int
constexpr size_t OFF_CS1 = AL(OFF_CURSORS + (size_t)N * 4);       // 128 f
constexpr size_t OFF_CQ1 = OFF_CS1 + 512;
constexpr size_t OFF_CS2 = OFF_CQ1 + 512;
constexpr size_t OFF_CQ2 = OFF_CS2 + 512;
constexpr size_t ZERO_END = OFF_CQ2 + 512;                        // memset [0, ZERO_END)
constexpr size_t OFF_OFFS = AL(ZERO_END);                         // N int
constexpr size_t OFF_BSUM = AL(OFF_OFFS + (size_t)N * 4);         // 256 int
constexpr size_t OFF_BPREF = AL(OFF_BSUM + 1024);                 // 256 int
constexpr size_t OFF_SS1 = AL(OFF_BPREF + 1024);                  // 256 f
constexpr size_t OFF_SS2 = AL(OFF_SS1 + 1024);                    // 256 f
constexpr size_t OFF_CSR = AL(OFF_SS2 + 1024);                    // E int
constexpr size_t OFF_WTQKV = AL(OFF_CSR + (size_t)E * 4);         // 3*128*128 bf16
constexpr size_t OFF_WOT = AL(OFF_WTQKV + 49152 * 2);             // 128*128 bf16
constexpr size_t OFF_W1T = AL(OFF_WOT + 16384 * 2);               // 256*128 bf16
constexpr size_t OFF_W2T = AL(OFF_W1T + 32768 * 2);               // 128*256 bf16
constexpr size_t OFF_QKV = AL(OFF_W2T + 32768 * 2);               // 3*N*128 bf16 (later reused for Z: N*256 bf16)
constexpr size_t OFF_AGG = AL(OFF_QKV + (size_t)3 * N * 128 * 2); // N*128 bf16 (later reused for Hn)
constexpr size_t OFF_Y = AL(OFF_AGG + (size_t)N * 128 * 2);       // N*128 f32
constexpr size_t OFF_T = AL(OFF_Y + (size_t)N * 128 * 4);         // N*128 f32

// ---------- weight transpose+cast (f32 [k][n] -> bf16 [n][k]) ----------
__global__ void prep_w(const float* __restrict__ WQ, const float* __restrict__ WK,
                       const float* __restrict__ WV, const float* __restrict__ WO,
                       const float* __restrict__ W1, const float* __restrict__ W2,
                       unsigned short* __restrict__ WtQKV, unsigned short* __restrict__ WOt,
                       unsigned short* __restrict__ W1t, unsigned short* __restrict__ W2t) {
    int gid = blockIdx.x * 256 + threadIdx.x;  // 131072 total
    if (gid < 49152) {
        int s = gid >> 14, r = gid & 16383;
        int n = r >> 7, k = r & 127;
        const float* W = (s == 0) ? WQ : (s == 1) ? WK : WV;
        WtQKV[gid] = f2b(W[k * 128 + n]);
    } else if (gid < 65536) {
        int r = gid - 49152;
        int n = r >> 7, k = r & 127;
        WOt[r] = f2b(WO[k * 128 + n]);
    } else if (gid < 98304) {
        int r = gid - 65536;
        int n = r >> 7, k = r & 127;       // n<256, k<128, W1 is [128][256]
        W1t[r] = f2b(W1[k * 256 + n]);
    } else {
        int r = gid - 98304;
        int n = r >> 8, k = r & 255;       // n<128, k<256, W2 is [256][128]
        W2t[r] = f2b(W2[k * 128 + n]);
    }
}

// ---------- CSR build ----------
__global__ void hist_k(const int* __restrict__ eidx, int* __restrict__ counts) {
    int e = blockIdx.x * 256 + threadIdx.x;
    if (e < E) atomicAdd(&counts[eidx[E + e]], 1);
}

__global__ void scan_a(const int* __restrict__ counts, int* __restrict__ offs, int* __restrict__ bsum) {
    __shared__ int sm[256];
    int t = threadIdx.x;
    int gi = blockIdx.x * 256 + t;
    int v = (gi < N) ? counts[gi] : 0;
    sm[t] = v;
    __syncthreads();
    for (int o = 1; o < 256; o <<= 1) {
        int x = (t >= o) ? sm[t - o] : 0;
        __syncthreads();
        sm[t] += x;
        __syncthreads();
    }
    if (gi < N) offs[gi] = sm[t] - v;  // block-local exclusive
    if (t == 255) bsum[blockIdx.x] = sm[255];
}

__global__ void scan_b(const int* __restrict__ bsum, int* __restrict__ bpref) {
    __shared__ int sm[256];
    int t = threadIdx.x;
    int v = (t < 196) ? bsum[t] : 0;
    sm[t] = v;
    __syncthreads();
    for (int o = 1; o < 256; o <<= 1) {
        int x = (t >= o) ? sm[t - o] : 0;
        __syncthreads();
        sm[t] += x;
        __syncthreads();
    }
    bpref[t] = sm[t] - v;
}

__global__ void scan_c(int* __restrict__ offs, const int* __restrict__ bpref) {
    int gi = blockIdx.x * 256 + threadIdx.x;
    if (gi < N) offs[gi] += bpref[blockIdx.x];
}

__global__ void fill_k(const int* __restrict__ eidx, const int* __restrict__ offs,
                       int* __restrict__ cursors, int* __restrict__ csr) {
    int e = blockIdx.x * 256 + threadIdx.x;
    if (e < E) {
        int d = eidx[E + e];
        int p = atomicAdd(&cursors[d], 1);
        csr[offs[d] + p] = eidx[e];
    }
}

// ---------- MFMA GEMM: C[N,128-slice] = A[N,KTOT](bf16) @ Wt^T ----------
// MODE 0: out bf16 (QKV, grid.y selects weight slice + output slice)
// MODE 1: out f32 = acc + bias + ex1(x, f32)
// MODE 2: out bf16 = relu(acc + bias[gcol]), out ld=256, grid.y = col half
// MODE 3: out f32 = acc + bias + (ex1*ex2_scale + ex2_shift)   (residual re-normalized from y)
template <int KTOT, int ASRC, int MODE>
__global__ __launch_bounds__(256) void gemm_k(const void* __restrict__ Av,
                                              const unsigned short* __restrict__ Wt,
                                              void* __restrict__ Outv,
                                              const float* __restrict__ bias,
                                              const float* __restrict__ ex1,
                                              const float* __restrict__ ex2) {
    constexpr int KCH = KTOT / 128;
    __shared__ unsigned short As[64][136];
    __shared__ unsigned short Bs[128][136];
    const int tid = threadIdx.x;
    const int lane = tid & 63, wave = tid >> 6;
    const int quad = lane >> 4, l15 = lane & 15;
    const int wr = wave >> 1, wc = wave & 1;
    const int row0 = blockIdx.x * 64;
    const int gy = blockIdx.y;
    const unsigned short* WtS = Wt + (size_t)gy * 128 * KTOT;

    f32x4 acc[2][4];
#pragma unroll
    for (int i = 0; i < 2; i++)
#pragma unroll
        for (int j = 0; j < 4; j++) acc[i][j] = (f32x4){0.f, 0.f, 0.f, 0.f};

    for (int kc = 0; kc < KCH; kc++) {
        __syncthreads();
        // stage A (64 x 128 bf16)
#pragma unroll
        for (int it = 0; it < 4; it++) {
            int c = tid + it * 256;
            int r = c >> 4, k8 = (c & 15) * 8;
            int grow = row0 + r;
            uint4 val = {0u, 0u, 0u, 0u};
            if (grow < N) {
                if (ASRC == 1) {
                    val = *(const uint4*)((const unsigned short*)Av + (size_t)grow * KTOT + kc * 128 + k8);
                } else {
                    const float* ap = (const float*)Av + (size_t)grow * 128 + k8;
                    float4 f0 = *(const float4*)ap;
                    float4 f1 = *(const float4*)(ap + 4);
                    val.x = pack2(f0.x, f0.y);
                    val.y = pack2(f0.z, f0.w);
                    val.z = pack2(f1.x, f1.y);
                    val.w = pack2(f1.z, f1.w);
                }
            }
            *(uint4*)&As[r][k8] = val;
        }
        // stage B (128 x 128 bf16), already [n][k]
#pragma unroll
        for (int it = 0; it < 8; it++) {
            int c = tid + it * 256;
            int n = c >> 4, k8 = (c & 15) * 8;
            *(uint4*)&Bs[n][k8] = *(const uint4*)(WtS + (size_t)n * KTOT + kc * 128 + k8);
        }
        __syncthreads();
#pragma unroll
        for (int ks = 0; ks < 4; ks++) {
            int k0 = ks * 32 + quad * 8;
            bfrag8 a0 = *(const bfrag8*)&As[wr * 32 + l15][k0];
            bfrag8 a1 = *(const bfrag8*)&As[wr * 32 + 16 + l15][k0];
#pragma unroll
            for (int jn = 0; jn < 4; jn++) {
                bfrag8 b = *(const bfrag8*)&Bs[wc * 64 + jn * 16 + l15][k0];
                acc[0][jn] = __builtin_amdgcn_mfma_f32_16x16x32_bf16(a0, b, acc[0][jn], 0, 0, 0);
                acc[1][jn] = __builtin_amdgcn_mfma_f32_16x16x32_bf16(a1, b, acc[1][jn], 0, 0, 0);
            }
        }
    }

    // epilogue: C row = quad*4+reg, col = l15 (verified layout)
#pragma unroll
    for (int i = 0; i < 2; i++) {
        int rbase = row0 + wr * 32 + i * 16 + quad * 4;
#pragma unroll
        for (int jn = 0; jn < 4; jn++) {
            int cl = wc * 64 + jn * 16 + l15;
#pragma unroll
            for (int r = 0; r < 4; r++) {
                int grow = rbase + r;
                if (grow < N) {
                    float v = acc[i][jn][r];
                    if (MODE == 0) {
                        ((unsigned short*)Outv)[(size_t)gy * N * 128 + (size_t)grow * 128 + cl] = f2b(v);
                    } else if (MODE == 1) {
                        v += bias[cl] + ex1[(size_t)grow * 128 + cl];
                        ((float*)Outv)[(size_t)grow * 128 + cl] = v;
                    } else if (MODE == 2) {
                        int gc = gy * 128 + cl;
                        v += bias[gc];
                        v = fmaxf(v, 0.f);
                        ((unsigned short*)Outv)[(size_t)grow * 256 + gc] = f2b(v);
                    } else {
                        float hn = ex1[(size_t)grow * 128 + cl] * ex2[cl] + ex2[128 + cl];
                        v += bias[cl] + hn;
                        ((float*)Outv)[(size_t)grow * 128 + cl] = v;
                    }
                }
            }
        }
    }
}

// ---------- attention: one wave per destination node ----------
__global__ __launch_bounds__(256) void attn_k(const unsigned short* __restrict__ qkv,
                                              const int* __restrict__ csr,
                                              const int* __restrict__ offs,
                                              const int* __restrict__ counts,
                                              unsigned short* __restrict__ agg) {
    const int wave = threadIdx.x >> 6;
    const int i = blockIdx.x * 4 + wave;
    if (i >= N) return;
    const int lane = threadIdx.x & 63;
    const unsigned short* Qb = qkv + (size_t)i * 128;
    const unsigned short* Kb = qkv + (size_t)N * 128;
    const unsigned short* Vb = qkv + (size_t)2 * N * 128;
    float2 q = ld2b(Qb + lane * 2);
    int off = offs[i];
    int deg = counts[i];
    float s = 0.f, ax = 0.f, ay = 0.f;
    for (int e = 0; e < deg; e++) {
        int j = csr[off + e];
        float2 k = ld2b(Kb + (size_t)j * 128 + lane * 2);
        float p = q.x * k.x + q.y * k.y;
        p += __shfl_xor(p, 1, 64);
        p += __shfl_xor(p, 2, 64);
        p += __shfl_xor(p, 4, 64);  // all 8 lanes of this head share the dot
        float sc = fminf(fmaxf(p * 0.25f, -5.f), 5.f);
        float w = __expf(sc);
        float2 v = ld2b(Vb + (size_t)j * 128 + lane * 2);
        s += w;
        ax += w * v.x;
        ay += w * v.y;
    }
    float inv = 1.0f / (s + 1e-16f);
    unsigned o = pack2(ax * inv, ay * inv);
    *(unsigned*)(agg + (size_t)i * 128 + lane * 2) = o;
}

// ---------- column stats (sum, sumsq) over rows ----------
__global__ void colstats_k(const float* __restrict__ Y, float* __restrict__ sum,
                           float* __restrict__ sumsq) {
    __shared__ float sm[256];
    const int t = threadIdx.x;
    const int col = t & 127, half = t >> 7;
    constexpr int CHUNK = (N + 127) / 128;  // 391
    int r0 = blockIdx.x * CHUNK;
    int r1 = min(N, r0 + CHUNK);
    float s = 0.f, q = 0.f;
    for (int r = r0 + half; r < r1; r += 2) {
        float v = Y[(size_t)r * 128 + col];
        s += v;
        q += v * v;
    }
    sm[t] = s;
    __syncthreads();
    if (t < 128) atomicAdd(&sum[col], sm[t] + sm[t + 128]);
    __syncthreads();
    sm[t] = q;
    __syncthreads();
    if (t < 128) atomicAdd(&sumsq[col], sm[t] + sm[t + 128]);
}

__global__ void bnfin_k(const float* __restrict__ sum, const float* __restrict__ sq,
                        const float* __restrict__ g, const float* __restrict__ be,
                        float* __restrict__ ss) {
    int c = threadIdx.x;
    float mu = sum[c] * (1.f / N);
    float var = sq[c] * (1.f / N) - mu * mu;
    float sc = g[c] * rsqrtf(var + 1e-5f);
    ss[c] = sc;
    ss[128 + c] = be[c] - mu * sc;
}

__global__ void bnapply_k(const float* __restrict__ Y, const float* __restrict__ ss,
                          unsigned short* __restrict__ Hn) {
    size_t idx = ((size_t)blockIdx.x * 256 + threadIdx.x) * 4;
    if (idx >= (size_t)N * 128) return;
    int c0 = (int)(idx & 127);
    float4 y = *(const float4*)(Y + idx);
    uint2 o;
    o.x = pack2(y.x * ss[c0] + ss[128 + c0], y.y * ss[c0 + 1] + ss[129 + c0]);
    o.y = pack2(y.z * ss[c0 + 2] + ss[130 + c0], y.w * ss[c0 + 3] + ss[131 + c0]);
    *(uint2*)(Hn + idx) = o;
}

__global__ void bnout_k(const float* __restrict__ T, const float* __restrict__ ss,
                        float* __restrict__ Out) {
    size_t idx = ((size_t)blockIdx.x * 256 + threadIdx.x) * 4;
    if (idx >= (size_t)N * 128) return;
    int c0 = (int)(idx & 127);
    float4 t = *(const float4*)(T + idx);
    float4 o;
    o.x = t.x * ss[c0] + ss[128 + c0];
    o.y = t.y * ss[c0 + 1] + ss[129 + c0];
    o.z = t.z * ss[c0 + 2] + ss[130 + c0];
    o.w = t.w * ss[c0 + 3] + ss[131 + c0];
    *(float4*)(Out + idx) = o;
}

extern "C" void kernel_launch(void* const* d_in, const int* in_sizes, int n_in,
                              void* d_out, int out_size, void* d_ws, size_t ws_size,
                              hipStream_t stream) {
    const float* x = (const float*)d_in[0];
    const int* eidx = (const int*)d_in[1];
    const float* WQ = (const float*)d_in[2];
    const float* WK = (const float*)d_in[3];
    const float* WV = (const float*)d_in[4];
    const float* WO = (const float*)d_in[5];
    const float* bO = (const float*)d_in[6];
    const float* W1 = (const float*)d_in[7];
    const float* b1 = (const float*)d_in[8];
    const float* W2 = (const float*)d_in[9];
    const float* b2 = (const float*)d_in[10];
    const float* g1 = (const float*)d_in[11];
    const float* be1 = (const float*)d_in[12];
    const float* g2 = (const float*)d_in[13];
    const float* be2 = (const float*)d_in[14];
    float* out = (float*)d_out;

    char* ws = (char*)d_ws;
    int* counts = (int*)(ws + OFF_COUNTS);
    int* cursors = (int*)(ws + OFF_CURSORS);
    float* cs1 = (float*)(ws + OFF_CS1);
    float* cq1 = (float*)(ws + OFF_CQ1);
    float* cs2 = (float*)(ws + OFF_CS2);
    float* cq2 = (float*)(ws + OFF_CQ2);
    int* offs = (int*)(ws + OFF_OFFS);
    int* bsum = (int*)(ws + OFF_BSUM);
    int* bpref = (int*)(ws + OFF_BPREF);
    float* ss1 = (float*)(ws + OFF_SS1);
    float* ss2 = (float*)(ws + OFF_SS2);
    int* csr = (int*)(ws + OFF_CSR);
    unsigned short* WtQKV = (unsigned short*)(ws + OFF_WTQKV);
    unsigned short* WOt = (unsigned short*)(ws + OFF_WOT);
    unsigned short* W1t = (unsigned short*)(ws + OFF_W1T);
    unsigned short* W2t = (unsigned short*)(ws + OFF_W2T);
    unsigned short* qkv = (unsigned short*)(ws + OFF_QKV);
    unsigned short* Zb = (unsigned short*)(ws + OFF_QKV);  // reuse (qkv dead)
    unsigned short* agg = (unsigned short*)(ws + OFF_AGG);
    unsigned short* Hn = (unsigned short*)(ws + OFF_AGG);  // reuse (agg dead)
    float* Yb = (float*)(ws + OFF_Y);
    float* Tb = (float*)(ws + OFF_T);

    hipMemsetAsync(ws, 0, ZERO_END, stream);
    prep_w<<<512, 256, 0, stream>>>(WQ, WK, WV, WO, W1, W2, WtQKV, WOt, W1t, W2t);

    // CSR build
    const int EB = (E + 255) / 256;  // 1954
    hist_k<<<EB, 256, 0, stream>>>(eidx, counts);
    scan_a<<<196, 256, 0, stream>>>(counts, offs, bsum);
    scan_b<<<1, 256, 0, stream>>>(bsum, bpref);
    scan_c<<<196, 256, 0, stream>>>(offs, bpref);
    fill_k<<<EB, 256, 0, stream>>>(eidx, offs, cursors, csr);

    const int MB = (N + 63) / 64;  // 782
    // QKV
    gemm_k<128, 0, 0><<<dim3(MB, 3), 256, 0, stream>>>(x, WtQKV, qkv, nullptr, nullptr, nullptr);
    // attention
    attn_k<<<(N + 3) / 4, 256, 0, stream>>>(qkv, csr, offs, counts, agg);
    // y = agg@WO + bO + x
    gemm_k<128, 1, 1><<<dim3(MB, 1), 256, 0, stream>>>(agg, WOt, Yb, bO, x, nullptr);
    // BN1
    colstats_k<<<128, 256, 0, stream>>>(Yb, cs1, cq1);
    bnfin_k<<<1, 128, 0, stream>>>(cs1, cq1, g1, be1, ss1);
    bnapply_k<<<(N * 128 / 4 + 255) / 256, 256, 0, stream>>>(Yb, ss1, Hn);
    // FFN
    gemm_k<128, 1, 2><<<dim3(MB, 2), 256, 0, stream>>>(Hn, W1t, Zb, b1, nullptr, nullptr);
    gemm_k<256, 1, 3><<<dim3(MB, 1), 256, 0, stream>>>(Zb, W2t, Tb, b2, Yb, ss1);
    // BN2 + output
    colstats_k<<<128, 256, 0, stream>>>(Tb, cs2, cq2);
    bnfin_k<<<1, 128, 0, stream>>>(cs2, cq2, g2, be2, ss2);
    bnout_k<<<(N * 128 / 4 + 255) / 256, 256, 0, stream>>>(Tb, ss2, out);
}

// Round 2
// 345.304 us; speedup vs baseline: 1.2779x; 1.2779x over previous
//
#include <hip/hip_runtime.h>

#define DEV __device__ __forceinline__

constexpr int N = 50000;
constexpr int E = 500000;
constexpr int D = 128;
constexpr int DFF = 256;

typedef __attribute__((ext_vector_type(8))) short bfrag8;
typedef __attribute__((ext_vector_type(4))) float f32x4;

// ---------- helpers ----------
DEV unsigned short f2b(float f) {
    unsigned u = __float_as_uint(f);
    unsigned r = (u + 0x7FFFu + ((u >> 16) & 1u)) >> 16;
    return (unsigned short)r;
}
DEV unsigned pack2(float a, float b) {
    return (unsigned)f2b(a) | ((unsigned)f2b(b) << 16);
}
DEV float2 ld2b(const unsigned short* p) {
    unsigned u = *(const unsigned*)p;
    float2 r;
    r.x = __uint_as_float(u << 16);
    r.y = __uint_as_float(u & 0xFFFF0000u);
    return r;
}

// ---------- workspace layout (bytes) ----------
constexpr size_t AL(size_t x) { return (x + 511) & ~(size_t)511; }
constexpr size_t OFF_COUNTS = 0;                                  // N int
constexpr size_t OFF_CURSORS = AL(OFF_COUNTS + (size_t)N * 4);    // N int
constexpr size_t OFF_CS1 = AL(OFF_CURSORS + (size_t)N * 4);       // 128 f
constexpr size_t OFF_CQ1 = OFF_CS1 + 512;
constexpr size_t OFF_CS2 = OFF_CQ1 + 512;
constexpr size_t OFF_CQ2 = OFF_CS2 + 512;
constexpr size_t ZERO_END = OFF_CQ2 + 512;                        // memset [0, ZERO_END)
constexpr size_t OFF_OFFS = AL(ZERO_END);                         // N int
constexpr size_t OFF_BSUM = AL(OFF_OFFS + (size_t)N * 4);         // 256 int
constexpr size_t OFF_BPREF = AL(OFF_BSUM + 1024);                 // 256 int
constexpr size_t OFF_SS1 = AL(OFF_BPREF + 1024);                  // 256 f
constexpr size_t OFF_SS2 = AL(OFF_SS1 + 1024);                    // 256 f
constexpr size_t OFF_CSR = AL(OFF_SS2 + 1024);                    // E int
constexpr size_t OFF_WTQKV = AL(OFF_CSR + (size_t)E * 4);         // 3*128*128 bf16
constexpr size_t OFF_WOT = AL(OFF_WTQKV + 49152 * 2);             // 128*128 bf16
constexpr size_t OFF_W1T = AL(OFF_WOT + 16384 * 2);               // 256*128 bf16
constexpr size_t OFF_W2T = AL(OFF_W1T + 32768 * 2);               // 128*256 bf16
constexpr size_t OFF_QKV = AL(OFF_W2T + 32768 * 2);               // 3*N*128 bf16 (later reused for Z: N*256 bf16)
constexpr size_t OFF_AGG = AL(OFF_QKV + (size_t)3 * N * 128 * 2); // N*128 bf16
constexpr size_t OFF_Y = AL(OFF_AGG + (size_t)N * 128 * 2);       // N*128 f32
constexpr size_t OFF_T = AL(OFF_Y + (size_t)N * 128 * 4);         // N*128 f32

// ---------- weight transpose+cast (f32 [k][n] -> bf16 [n][k]) ----------
__global__ void prep_w(const float* __restrict__ WQ, const float* __restrict__ WK,
                       const float* __restrict__ WV, const float* __restrict__ WO,
                       const float* __restrict__ W1, const float* __restrict__ W2,
                       unsigned short* __restrict__ WtQKV, unsigned short* __restrict__ WOt,
                       unsigned short* __restrict__ W1t, unsigned short* __restrict__ W2t) {
    int gid = blockIdx.x * 256 + threadIdx.x;  // 131072 total
    if (gid < 49152) {
        int s = gid >> 14, r = gid & 16383;
        int n = r >> 7, k = r & 127;
        const float* W = (s == 0) ? WQ : (s == 1) ? WK : WV;
        WtQKV[gid] = f2b(W[k * 128 + n]);
    } else if (gid < 65536) {
        int r = gid - 49152;
        int n = r >> 7, k = r & 127;
        WOt[r] = f2b(WO[k * 128 + n]);
    } else if (gid < 98304) {
        int r = gid - 65536;
        int n = r >> 7, k = r & 127;       // n<256, k<128, W1 is [128][256]
        W1t[r] = f2b(W1[k * 256 + n]);
    } else {
        int r = gid - 98304;
        int n = r >> 8, k = r & 255;       // n<128, k<256, W2 is [256][128]
        W2t[r] = f2b(W2[k * 128 + n]);
    }
}

// ---------- CSR build ----------
__global__ void hist_k(const int* __restrict__ eidx, int* __restrict__ counts) {
    int e = blockIdx.x * 256 + threadIdx.x;
    if (e < E) atomicAdd(&counts[eidx[E + e]], 1);
}

__global__ void scan_a(const int* __restrict__ counts, int* __restrict__ offs, int* __restrict__ bsum) {
    __shared__ int sm[256];
    int t = threadIdx.x;
    int gi = blockIdx.x * 256 + t;
    int v = (gi < N) ? counts[gi] : 0;
    sm[t] = v;
    __syncthreads();
    for (int o = 1; o < 256; o <<= 1) {
        int x = (t >= o) ? sm[t - o] : 0;
        __syncthreads();
        sm[t] += x;
        __syncthreads();
    }
    if (gi < N) offs[gi] = sm[t] - v;  // block-local exclusive
    if (t == 255) bsum[blockIdx.x] = sm[255];
}

__global__ void scan_b(const int* __restrict__ bsum, int* __restrict__ bpref) {
    __shared__ int sm[256];
    int t = threadIdx.x;
    int v = (t < 196) ? bsum[t] : 0;
    sm[t] = v;
    __syncthreads();
    for (int o = 1; o < 256; o <<= 1) {
        int x = (t >= o) ? sm[t - o] : 0;
        __syncthreads();
        sm[t] += x;
        __syncthreads();
    }
    bpref[t] = sm[t] - v;
}

__global__ void scan_c(int* __restrict__ offs, const int* __restrict__ bpref) {
    int gi = blockIdx.x * 256 + threadIdx.x;
    if (gi < N) offs[gi] += bpref[blockIdx.x];
}

__global__ void fill_k(const int* __restrict__ eidx, const int* __restrict__ offs,
                       int* __restrict__ cursors, int* __restrict__ csr) {
    int e = blockIdx.x * 256 + threadIdx.x;
    if (e < E) {
        int d = eidx[E + e];
        int p = atomicAdd(&cursors[d], 1);
        csr[offs[d] + p] = eidx[e];
    }
}

// ---------- MFMA GEMM: C[N,128-slice] = A[N,KTOT](bf16) @ Wt^T ----------
// ASRC 0: A = f32, cast bf16 in staging
// ASRC 1: A = bf16
// ASRC 2: A = f32, apply BN (ssA scale/shift per k-col) then cast bf16 in staging
// MODE 0: out bf16 (QKV, grid.y selects weight slice + output slice)
// MODE 1: out f32 = acc + bias + ex1   (+fused col stats -> csum/cqsum)
// MODE 2: out bf16 = relu(acc + bias[gcol]), out ld=256, grid.y = col half
// MODE 3: out f32 = acc + bias + (ex1*ssA_scale + ssA_shift)  (+fused col stats)
template <int KTOT, int ASRC, int MODE>
__global__ __launch_bounds__(256) void gemm_k(const void* __restrict__ Av,
                                              const unsigned short* __restrict__ Wt,
                                              void* __restrict__ Outv,
                                              const float* __restrict__ bias,
                                              const float* __restrict__ ex1,
                                              const float* __restrict__ ssA,
                                              float* __restrict__ csum,
                                              float* __restrict__ cqsum) {
    constexpr int KCH = KTOT / 128;
    __shared__ unsigned short As[64][136];
    __shared__ unsigned short Bs[128][136];
    const int tid = threadIdx.x;
    const int lane = tid & 63, wave = tid >> 6;
    const int quad = lane >> 4, l15 = lane & 15;
    const int wr = wave >> 1, wc = wave & 1;
    const int row0 = blockIdx.x * 64;
    const int gy = blockIdx.y;
    const unsigned short* WtS = Wt + (size_t)gy * 128 * KTOT;

    f32x4 acc[2][4];
#pragma unroll
    for (int i = 0; i < 2; i++)
#pragma unroll
        for (int j = 0; j < 4; j++) acc[i][j] = (f32x4){0.f, 0.f, 0.f, 0.f};

    for (int kc = 0; kc < KCH; kc++) {
        __syncthreads();
        // stage A (64 x 128 bf16)
#pragma unroll
        for (int it = 0; it < 4; it++) {
            int c = tid + it * 256;
            int r = c >> 4, k8 = (c & 15) * 8;
            int grow = row0 + r;
            uint4 val = {0u, 0u, 0u, 0u};
            if (grow < N) {
                if (ASRC == 1) {
                    val = *(const uint4*)((const unsigned short*)Av + (size_t)grow * KTOT + kc * 128 + k8);
                } else {
                    const float* ap = (const float*)Av + (size_t)grow * 128 + k8;
                    float4 f0 = *(const float4*)ap;
                    float4 f1 = *(const float4*)(ap + 4);
                    if (ASRC == 2) {
                        float4 sc0 = *(const float4*)(ssA + k8);
                        float4 sc1 = *(const float4*)(ssA + k8 + 4);
                        float4 sh0 = *(const float4*)(ssA + 128 + k8);
                        float4 sh1 = *(const float4*)(ssA + 128 + k8 + 4);
                        f0.x = f0.x * sc0.x + sh0.x;
                        f0.y = f0.y * sc0.y + sh0.y;
                        f0.z = f0.z * sc0.z + sh0.z;
                        f0.w = f0.w * sc0.w + sh0.w;
                        f1.x = f1.x * sc1.x + sh1.x;
                        f1.y = f1.y * sc1.y + sh1.y;
                        f1.z = f1.z * sc1.z + sh1.z;
                        f1.w = f1.w * sc1.w + sh1.w;
                    }
                    val.x = pack2(f0.x, f0.y);
                    val.y = pack2(f0.z, f0.w);
                    val.z = pack2(f1.x, f1.y);
                    val.w = pack2(f1.z, f1.w);
                }
            }
            *(uint4*)&As[r][k8] = val;
        }
        // stage B (128 x 128 bf16), already [n][k]
#pragma unroll
        for (int it = 0; it < 8; it++) {
            int c = tid + it * 256;
            int n = c >> 4, k8 = (c & 15) * 8;
            *(uint4*)&Bs[n][k8] = *(const uint4*)(WtS + (size_t)n * KTOT + kc * 128 + k8);
        }
        __syncthreads();
#pragma unroll
        for (int ks = 0; ks < 4; ks++) {
            int k0 = ks * 32 + quad * 8;
            bfrag8 a0 = *(const bfrag8*)&As[wr * 32 + l15][k0];
            bfrag8 a1 = *(const bfrag8*)&As[wr * 32 + 16 + l15][k0];
#pragma unroll
            for (int jn = 0; jn < 4; jn++) {
                bfrag8 b = *(const bfrag8*)&Bs[wc * 64 + jn * 16 + l15][k0];
                acc[0][jn] = __builtin_amdgcn_mfma_f32_16x16x32_bf16(a0, b, acc[0][jn], 0, 0, 0);
                acc[1][jn] = __builtin_amdgcn_mfma_f32_16x16x32_bf16(a1, b, acc[1][jn], 0, 0, 0);
            }
        }
    }

    // epilogue: C row = quad*4+reg, col = l15 (verified layout)
    float colS[4] = {0.f, 0.f, 0.f, 0.f}, colQ[4] = {0.f, 0.f, 0.f, 0.f};
#pragma unroll
    for (int i = 0; i < 2; i++) {
        int rbase = row0 + wr * 32 + i * 16 + quad * 4;
#pragma unroll
        for (int jn = 0; jn < 4; jn++) {
            int cl = wc * 64 + jn * 16 + l15;
#pragma unroll
            for (int r = 0; r < 4; r++) {
                int grow = rbase + r;
                if (grow < N) {
                    float v = acc[i][jn][r];
                    if (MODE == 0) {
                        ((unsigned short*)Outv)[(size_t)gy * N * 128 + (size_t)grow * 128 + cl] = f2b(v);
                    } else if (MODE == 1) {
                        v += bias[cl] + ex1[(size_t)grow * 128 + cl];
                        ((float*)Outv)[(size_t)grow * 128 + cl] = v;
                        colS[jn] += v;
                        colQ[jn] += v * v;
                    } else if (MODE == 2) {
                        int gc = gy * 128 + cl;
                        v += bias[gc];
                        v = fmaxf(v, 0.f);
                        ((unsigned short*)Outv)[(size_t)grow * 256 + gc] = f2b(v);
                    } else {
                        float hn = ex1[(size_t)grow * 128 + cl] * ssA[cl] + ssA[128 + cl];
                        v += bias[cl] + hn;
                        ((float*)Outv)[(size_t)grow * 128 + cl] = v;
                        colS[jn] += v;
                        colQ[jn] += v * v;
                    }
                }
            }
        }
    }

    if (MODE == 1 || MODE == 3) {
        // per-block column stats: quad-shfl reduce -> LDS -> 1 global atomic/thread
        __syncthreads();
        float* smf = (float*)&As[0][0];
        smf[tid] = 0.f;
        __syncthreads();
#pragma unroll
        for (int jn = 0; jn < 4; jn++) {
            float s = colS[jn], q = colQ[jn];
            s += __shfl_xor(s, 16, 64);
            q += __shfl_xor(q, 16, 64);
            s += __shfl_xor(s, 32, 64);
            q += __shfl_xor(q, 32, 64);
            if (quad == 0) {
                int cl = wc * 64 + jn * 16 + l15;
                atomicAdd(&smf[cl], s);
                atomicAdd(&smf[128 + cl], q);
            }
        }
        __syncthreads();
        if (tid < 128)
            atomicAdd(&csum[tid], smf[tid]);
        else
            atomicAdd(&cqsum[tid - 128], smf[tid]);
    }
}

// ---------- attention: one wave per destination node ----------
__global__ __launch_bounds__(256) void attn_k(const unsigned short* __restrict__ qkv,
                                              const int* __restrict__ csr,
                                              const int* __restrict__ offs,
                                              const int* __restrict__ counts,
                                              unsigned short* __restrict__ agg) {
    const int wave = threadIdx.x >> 6;
    const int i = blockIdx.x * 4 + wave;
    if (i >= N) return;
    const int lane = threadIdx.x & 63;
    const unsigned short* Qb = qkv;
    const unsigned short* Kb = qkv + (size_t)N * 128;
    const unsigned short* Vb = qkv + (size_t)2 * N * 128;
    float2 q = ld2b(Qb + (size_t)i * 128 + lane * 2);
    int off = offs[i];
    int deg = counts[i];
    float s = 0.f, ax = 0.f, ay = 0.f;
    for (int base = 0; base < deg; base += 64) {
        int rem = deg - base;
        if (rem > 64) rem = 64;
        int myj = (lane < rem) ? csr[off + base + lane] : 0;
        int e = 0;
        for (; e + 4 <= rem; e += 4) {
            int j0 = __shfl(myj, e, 64);
            int j1 = __shfl(myj, e + 1, 64);
            int j2 = __shfl(myj, e + 2, 64);
            int j3 = __shfl(myj, e + 3, 64);
            float2 k0 = ld2b(Kb + (size_t)j0 * 128 + lane * 2);
            float2 v0 = ld2b(Vb + (size_t)j0 * 128 + lane * 2);
            float2 k1 = ld2b(Kb + (size_t)j1 * 128 + lane * 2);
            float2 v1 = ld2b(Vb + (size_t)j1 * 128 + lane * 2);
            float2 k2 = ld2b(Kb + (size_t)j2 * 128 + lane * 2);
            float2 v2 = ld2b(Vb + (size_t)j2 * 128 + lane * 2);
            float2 k3 = ld2b(Kb + (size_t)j3 * 128 + lane * 2);
            float2 v3 = ld2b(Vb + (size_t)j3 * 128 + lane * 2);
            float p0 = q.x * k0.x + q.y * k0.y;
            float p1 = q.x * k1.x + q.y * k1.y;
            float p2 = q.x * k2.x + q.y * k2.y;
            float p3 = q.x * k3.x + q.y * k3.y;
            p0 += __shfl_xor(p0, 1, 64);
            p1 += __shfl_xor(p1, 1, 64);
            p2 += __shfl_xor(p2, 1, 64);
            p3 += __shfl_xor(p3, 1, 64);
            p0 += __shfl_xor(p0, 2, 64);
            p1 += __shfl_xor(p1, 2, 64);
            p2 += __shfl_xor(p2, 2, 64);
            p3 += __shfl_xor(p3, 2, 64);
            p0 += __shfl_xor(p0, 4, 64);
            p1 += __shfl_xor(p1, 4, 64);
            p2 += __shfl_xor(p2, 4, 64);
            p3 += __shfl_xor(p3, 4, 64);
            float w0 = __expf(fminf(fmaxf(p0 * 0.25f, -5.f), 5.f));
            float w1 = __expf(fminf(fmaxf(p1 * 0.25f, -5.f), 5.f));
            float w2 = __expf(fminf(fmaxf(p2 * 0.25f, -5.f), 5.f));
            float w3 = __expf(fminf(fmaxf(p3 * 0.25f, -5.f), 5.f));
            s += w0 + w1 + w2 + w3;
            ax += w0 * v0.x + w1 * v1.x + w2 * v2.x + w3 * v3.x;
            ay += w0 * v0.y + w1 * v1.y + w2 * v2.y + w3 * v3.y;
        }
        for (; e < rem; e++) {
            int j = __shfl(myj, e, 64);
            float2 k = ld2b(Kb + (size_t)j * 128 + lane * 2);
            float2 v = ld2b(Vb + (size_t)j * 128 + lane * 2);
            float p = q.x * k.x + q.y * k.y;
            p += __shfl_xor(p, 1, 64);
            p += __shfl_xor(p, 2, 64);
            p += __shfl_xor(p, 4, 64);
            float w = __expf(fminf(fmaxf(p * 0.25f, -5.f), 5.f));
            s += w;
            ax += w * v.x;
            ay += w * v.y;
        }
    }
    float inv = 1.0f / (s + 1e-16f);
    unsigned o = pack2(ax * inv, ay * inv);
    *(unsigned*)(agg + (size_t)i * 128 + lane * 2) = o;
}

__global__ void bnfin_k(const float* __restrict__ sum, const float* __restrict__ sq,
                        const float* __restrict__ g, const float* __restrict__ be,
                        float* __restrict__ ss) {
    int c = threadIdx.x;
    float mu = sum[c] * (1.f / N);
    float var = sq[c] * (1.f / N) - mu * mu;
    float sc = g[c] * rsqrtf(var + 1e-5f);
    ss[c] = sc;
    ss[128 + c] = be[c] - mu * sc;
}

__global__ void bnout_k(const float* __restrict__ T, const float* __restrict__ ss,
                        float* __restrict__ Out) {
    size_t idx = ((size_t)blockIdx.x * 256 + threadIdx.x) * 4;
    if (idx >= (size_t)N * 128) return;
    int c0 = (int)(idx & 127);
    float4 t = *(const float4*)(T + idx);
    float4 o;
    o.x = t.x * ss[c0] + ss[128 + c0];
    o.y = t.y * ss[c0 + 1] + ss[129 + c0];
    o.z = t.z * ss[c0 + 2] + ss[130 + c0];
    o.w = t.w * ss[c0 + 3] + ss[131 + c0];
    *(float4*)(Out + idx) = o;
}

extern "C" void kernel_launch(void* const* d_in, const int* in_sizes, int n_in,
                              void* d_out, int out_size, void* d_ws, size_t ws_size,
                              hipStream_t stream) {
    const float* x = (const float*)d_in[0];
    const int* eidx = (const int*)d_in[1];
    const float* WQ = (const float*)d_in[2];
    const float* WK = (const float*)d_in[3];
    const float* WV = (const float*)d_in[4];
    const float* WO = (const float*)d_in[5];
    const float* bO = (const float*)d_in[6];
    const float* W1 = (const float*)d_in[7];
    const float* b1 = (const float*)d_in[8];
    const float* W2 = (const float*)d_in[9];
    const float* b2 = (const float*)d_in[10];
    const float* g1 = (const float*)d_in[11];
    const float* be1 = (const float*)d_in[12];
    const float* g2 = (const float*)d_in[13];
    const float* be2 = (const float*)d_in[14];
    float* out = (float*)d_out;

    char* ws = (char*)d_ws;
    int* counts = (int*)(ws + OFF_COUNTS);
    int* cursors = (int*)(ws + OFF_CURSORS);
    float* cs1 = (float*)(ws + OFF_CS1);
    float* cq1 = (float*)(ws + OFF_CQ1);
    float* cs2 = (float*)(ws + OFF_CS2);
    float* cq2 = (float*)(ws + OFF_CQ2);
    int* offs = (int*)(ws + OFF_OFFS);
    int* bsum = (int*)(ws + OFF_BSUM);
    int* bpref = (int*)(ws + OFF_BPREF);
    float* ss1 = (float*)(ws + OFF_SS1);
    float* ss2 = (float*)(ws + OFF_SS2);
    int* csr = (int*)(ws + OFF_CSR);
    unsigned short* WtQKV = (unsigned short*)(ws + OFF_WTQKV);
    unsigned short* WOt = (unsigned short*)(ws + OFF_WOT);
    unsigned short* W1t = (unsigned short*)(ws + OFF_W1T);
    unsigned short* W2t = (unsigned short*)(ws + OFF_W2T);
    unsigned short* qkv = (unsigned short*)(ws + OFF_QKV);
    unsigned short* Zb = (unsigned short*)(ws + OFF_QKV);  // reuse (qkv dead)
    unsigned short* agg = (unsigned short*)(ws + OFF_AGG);
    float* Yb = (float*)(ws + OFF_Y);
    float* Tb = (float*)(ws + OFF_T);

    hipMemsetAsync(ws, 0, ZERO_END, stream);
    prep_w<<<512, 256, 0, stream>>>(WQ, WK, WV, WO, W1, W2, WtQKV, WOt, W1t, W2t);

    // CSR build
    const int EB = (E + 255) / 256;  // 1954
    hist_k<<<EB, 256, 0, stream>>>(eidx, counts);
    scan_a<<<196, 256, 0, stream>>>(counts, offs, bsum);
    scan_b<<<1, 256, 0, stream>>>(bsum, bpref);
    scan_c<<<196, 256, 0, stream>>>(offs, bpref);
    fill_k<<<EB, 256, 0, stream>>>(eidx, offs, cursors, csr);

    const int MB = (N + 63) / 64;  // 782
    // QKV
    gemm_k<128, 0, 0><<<dim3(MB, 3), 256, 0, stream>>>(x, WtQKV, qkv, nullptr, nullptr, nullptr, nullptr, nullptr);
    // attention
    attn_k<<<(N + 3) / 4, 256, 0, stream>>>(qkv, csr, offs, counts, agg);
    // y = agg@WO + bO + x   (+fused BN1 stats)
    gemm_k<128, 1, 1><<<dim3(MB, 1), 256, 0, stream>>>(agg, WOt, Yb, bO, x, nullptr, cs1, cq1);
    bnfin_k<<<1, 128, 0, stream>>>(cs1, cq1, g1, be1, ss1);
    // FFN gemm1: A = BN1(Yb) applied in staging, out = relu(.)
    gemm_k<128, 2, 2><<<dim3(MB, 2), 256, 0, stream>>>(Yb, W1t, Zb, b1, nullptr, ss1, nullptr, nullptr);
    // FFN gemm2: + residual BN1(Yb) recomputed from Yb (+fused BN2 stats)
    gemm_k<256, 1, 3><<<dim3(MB, 1), 256, 0, stream>>>(Zb, W2t, Tb, b2, Yb, ss1, cs2, cq2);
    bnfin_k<<<1, 128, 0, stream>>>(cs2, cq2, g2, be2, ss2);
    bnout_k<<<(N * 128 / 4 + 255) / 256, 256, 0, stream>>>(Tb, ss2, out);
}

// Round 3
// 323.096 us; speedup vs baseline: 1.3658x; 1.0687x over previous
//
#include <hip/hip_runtime.h>

#define DEV __device__ __forceinline__

constexpr int N = 50000;
constexpr int E = 500000;
constexpr int D = 128;
constexpr int DFF = 256;

typedef __attribute__((ext_vector_type(8))) short bfrag8;
typedef __attribute__((ext_vector_type(4))) float f32x4;

// ---------- helpers ----------
DEV unsigned short f2b(float f) {
    unsigned u = __float_as_uint(f);
    unsigned r = (u + 0x7FFFu + ((u >> 16) & 1u)) >> 16;
    return (unsigned short)r;
}
DEV unsigned pack2(float a, float b) {
    return (unsigned)f2b(a) | ((unsigned)f2b(b) << 16);
}
DEV float b2f(unsigned short v) { return __uint_as_float(((unsigned)v) << 16); }
DEV float2 ld2b(const unsigned short* p) {
    unsigned u = *(const unsigned*)p;
    float2 r;
    r.x = __uint_as_float(u << 16);
    r.y = __uint_as_float(u & 0xFFFF0000u);
    return r;
}

// ---------- workspace layout (bytes) ----------
constexpr size_t AL(size_t x) { return (x + 511) & ~(size_t)511; }
constexpr size_t OFF_COUNTS = 0;                                  // N int
constexpr size_t OFF_CURSORS = AL(OFF_COUNTS + (size_t)N * 4);    // N int
constexpr size_t OFF_CS1 = AL(OFF_CURSORS + (size_t)N * 4);       // 128 f
constexpr size_t OFF_CQ1 = OFF_CS1 + 512;
constexpr size_t OFF_CS2 = OFF_CQ1 + 512;
constexpr size_t OFF_CQ2 = OFF_CS2 + 512;
constexpr size_t ZERO_END = OFF_CQ2 + 512;                        // memset [0, ZERO_END)
constexpr size_t OFF_OFFS = AL(ZERO_END);                         // N int
constexpr size_t OFF_BSUM = AL(OFF_OFFS + (size_t)N * 4);         // 256 int
constexpr size_t OFF_BPREF = AL(OFF_BSUM + 1024);                 // 256 int
constexpr size_t OFF_SS1 = AL(OFF_BPREF + 1024);                  // 256 f
constexpr size_t OFF_SS2 = AL(OFF_SS1 + 1024);                    // 256 f
constexpr size_t OFF_B1P = AL(OFF_SS2 + 1024);                    // 256 f
constexpr size_t OFF_CSR = AL(OFF_B1P + 1024);                    // E int
constexpr size_t OFF_WTQKV = AL(OFF_CSR + (size_t)E * 4);         // 3*128*128 bf16 [n][k]
constexpr size_t OFF_WOT = AL(OFF_WTQKV + 49152 * 2);             // 128*128 bf16 [n][k]
constexpr size_t OFF_W1TF = AL(OFF_WOT + 16384 * 2);              // 256*128 f32 [n][k]
constexpr size_t OFF_W1S = AL(OFF_W1TF + 32768 * 4);              // 256*128 bf16 [n][k], scaled
constexpr size_t OFF_W2T = AL(OFF_W1S + 32768 * 2);               // 128*256 bf16 [n][k]
constexpr size_t OFF_QKV = AL(OFF_W2T + 32768 * 2);               // 3*N*128 bf16
constexpr size_t OFF_AGG = AL(OFF_QKV + (size_t)3 * N * 128 * 2); // N*128 bf16
constexpr size_t OFF_Y = AL(OFF_AGG + (size_t)N * 128 * 2);       // N*128 bf16
constexpr size_t OFF_T = AL(OFF_Y + (size_t)N * 128 * 2);         // N*128 bf16

// ---------- weight transpose+cast ----------
__global__ void prep_w(const float* __restrict__ WQ, const float* __restrict__ WK,
                       const float* __restrict__ WV, const float* __restrict__ WO,
                       const float* __restrict__ W1, const float* __restrict__ W2,
                       unsigned short* __restrict__ WtQKV, unsigned short* __restrict__ WOt,
                       float* __restrict__ W1tf, unsigned short* __restrict__ W2t) {
    int gid = blockIdx.x * 256 + threadIdx.x;  // 131072 total
    if (gid < 49152) {
        int s = gid >> 14, r = gid & 16383;
        int n = r >> 7, k = r & 127;
        const float* W = (s == 0) ? WQ : (s == 1) ? WK : WV;
        WtQKV[gid] = f2b(W[k * 128 + n]);
    } else if (gid < 65536) {
        int r = gid - 49152;
        int n = r >> 7, k = r & 127;
        WOt[r] = f2b(WO[k * 128 + n]);
    } else if (gid < 98304) {
        int r = gid - 65536;
        int n = r >> 7, k = r & 127;       // n<256, k<128, W1 is [128][256]
        W1tf[r] = W1[k * 256 + n];
    } else {
        int r = gid - 98304;
        int n = r >> 8, k = r & 255;       // n<128, k<256, W2 is [256][128]
        W2t[r] = f2b(W2[k * 128 + n]);
    }
}

// ---------- CSR build ----------
__global__ void hist_k(const int* __restrict__ eidx, int* __restrict__ counts) {
    int e = blockIdx.x * 256 + threadIdx.x;
    if (e < E) atomicAdd(&counts[eidx[E + e]], 1);
}

__global__ void scan_a(const int* __restrict__ counts, int* __restrict__ offs, int* __restrict__ bsum) {
    __shared__ int sm[256];
    int t = threadIdx.x;
    int gi = blockIdx.x * 256 + t;
    int v = (gi < N) ? counts[gi] : 0;
    sm[t] = v;
    __syncthreads();
    for (int o = 1; o < 256; o <<= 1) {
        int x = (t >= o) ? sm[t - o] : 0;
        __syncthreads();
        sm[t] += x;
        __syncthreads();
    }
    if (gi < N) offs[gi] = sm[t] - v;
    if (t == 255) bsum[blockIdx.x] = sm[255];
}

__global__ void scan_b(const int* __restrict__ bsum, int* __restrict__ bpref) {
    __shared__ int sm[256];
    int t = threadIdx.x;
    int v = (t < 196) ? bsum[t] : 0;
    sm[t] = v;
    __syncthreads();
    for (int o = 1; o < 256; o <<= 1) {
        int x = (t >= o) ? sm[t - o] : 0;
        __syncthreads();
        sm[t] += x;
        __syncthreads();
    }
    bpref[t] = sm[t] - v;
}

__global__ void scan_c(int* __restrict__ offs, const int* __restrict__ bpref) {
    int gi = blockIdx.x * 256 + threadIdx.x;
    if (gi < N) offs[gi] += bpref[blockIdx.x];
}

__global__ void fill_k(const int* __restrict__ eidx, const int* __restrict__ offs,
                       int* __restrict__ cursors, int* __restrict__ csr) {
    int e = blockIdx.x * 256 + threadIdx.x;
    if (e < E) {
        int d = eidx[E + e];
        int p = atomicAdd(&cursors[d], 1);
        csr[offs[d] + p] = eidx[e];
    }
}

// ---------- QKV: one block = 64 rows, loop over 3 weight slices ----------
__global__ __launch_bounds__(256) void qkv_k(const float* __restrict__ x,
                                             const unsigned short* __restrict__ WtQKV,
                                             unsigned short* __restrict__ qkv) {
    __shared__ unsigned short As[64][136];
    __shared__ unsigned short Bs[128][136];
    const int tid = threadIdx.x;
    const int lane = tid & 63, wave = tid >> 6;
    const int quad = lane >> 4, l15 = lane & 15;
    const int wr = wave >> 1, wc = wave & 1;
    const int row0 = blockIdx.x * 64;

    // stage A (64x128 f32 -> bf16)
#pragma unroll
    for (int it = 0; it < 4; it++) {
        int c = tid + it * 256;
        int r = c >> 4, k8 = (c & 15) * 8;
        int grow = row0 + r;
        uint4 val = {0u, 0u, 0u, 0u};
        if (grow < N) {
            const float* ap = x + (size_t)grow * 128 + k8;
            float4 f0 = *(const float4*)ap;
            float4 f1 = *(const float4*)(ap + 4);
            val.x = pack2(f0.x, f0.y);
            val.y = pack2(f0.z, f0.w);
            val.z = pack2(f1.x, f1.y);
            val.w = pack2(f1.z, f1.w);
        }
        *(uint4*)&As[r][k8] = val;
    }

    for (int s = 0; s < 3; s++) {
        if (s) __syncthreads();  // prior store done before Bs overwrite
        const unsigned short* WtS = WtQKV + (size_t)s * 16384;
#pragma unroll
        for (int it = 0; it < 8; it++) {
            int c = tid + it * 256;
            int n = c >> 4, k8 = (c & 15) * 8;
            *(uint4*)&Bs[n][k8] = *(const uint4*)(WtS + (size_t)n * 128 + k8);
        }
        __syncthreads();

        f32x4 acc[2][4];
#pragma unroll
        for (int i = 0; i < 2; i++)
#pragma unroll
            for (int j = 0; j < 4; j++) acc[i][j] = (f32x4){0.f, 0.f, 0.f, 0.f};
#pragma unroll
        for (int ks = 0; ks < 4; ks++) {
            int k0 = ks * 32 + quad * 8;
            bfrag8 a0 = *(const bfrag8*)&As[wr * 32 + l15][k0];
            bfrag8 a1 = *(const bfrag8*)&As[wr * 32 + 16 + l15][k0];
#pragma unroll
            for (int jn = 0; jn < 4; jn++) {
                bfrag8 b = *(const bfrag8*)&Bs[wc * 64 + jn * 16 + l15][k0];
                acc[0][jn] = __builtin_amdgcn_mfma_f32_16x16x32_bf16(a0, b, acc[0][jn], 0, 0, 0);
                acc[1][jn] = __builtin_amdgcn_mfma_f32_16x16x32_bf16(a1, b, acc[1][jn], 0, 0, 0);
            }
        }
        __syncthreads();  // Bs reads done -> reuse as bounce tile
        unsigned short(*Cs)[136] = (unsigned short(*)[136]) & Bs[0][0];
#pragma unroll
        for (int i = 0; i < 2; i++) {
            int rb = wr * 32 + i * 16 + quad * 4;
#pragma unroll
            for (int jn = 0; jn < 4; jn++) {
                int cl = wc * 64 + jn * 16 + l15;
#pragma unroll
                for (int r = 0; r < 4; r++) Cs[rb + r][cl] = f2b(acc[i][jn][r]);
            }
        }
        __syncthreads();
        unsigned short* outS = qkv + (size_t)s * N * 128;
#pragma unroll
        for (int j = 0; j < 4; j++) {
            int idx = tid + j * 256;          // 1024 uint4
            int u = idx >> 4, col8 = (idx & 15) * 8;
            int grow = row0 + u;
            if (grow < N) *(uint4*)(outS + (size_t)grow * 128 + col8) = *(const uint4*)&Cs[u][col8];
        }
    }
}

// ---------- attention: one wave per destination node ----------
__global__ __launch_bounds__(256) void attn_k(const unsigned short* __restrict__ qkv,
                                              const int* __restrict__ csr,
                                              const int* __restrict__ offs,
                                              const int* __restrict__ counts,
                                              unsigned short* __restrict__ agg) {
    const int wave = threadIdx.x >> 6;
    const int i = blockIdx.x * 4 + wave;
    if (i >= N) return;
    const int lane = threadIdx.x & 63;
    const unsigned short* Qb = qkv;
    const unsigned short* Kb = qkv + (size_t)N * 128;
    const unsigned short* Vb = qkv + (size_t)2 * N * 128;
    float2 q = ld2b(Qb + (size_t)i * 128 + lane * 2);
    int off = offs[i];
    int deg = counts[i];
    float s = 0.f, ax = 0.f, ay = 0.f;
    for (int base = 0; base < deg; base += 64) {
        int rem = deg - base;
        if (rem > 64) rem = 64;
        int myj = (lane < rem) ? csr[off + base + lane] : 0;
        int e = 0;
        for (; e + 4 <= rem; e += 4) {
            int j0 = __shfl(myj, e, 64);
            int j1 = __shfl(myj, e + 1, 64);
            int j2 = __shfl(myj, e + 2, 64);
            int j3 = __shfl(myj, e + 3, 64);
            float2 k0 = ld2b(Kb + (size_t)j0 * 128 + lane * 2);
            float2 v0 = ld2b(Vb + (size_t)j0 * 128 + lane * 2);
            float2 k1 = ld2b(Kb + (size_t)j1 * 128 + lane * 2);
            float2 v1 = ld2b(Vb + (size_t)j1 * 128 + lane * 2);
            float2 k2 = ld2b(Kb + (size_t)j2 * 128 + lane * 2);
            float2 v2 = ld2b(Vb + (size_t)j2 * 128 + lane * 2);
            float2 k3 = ld2b(Kb + (size_t)j3 * 128 + lane * 2);
            float2 v3 = ld2b(Vb + (size_t)j3 * 128 + lane * 2);
            float p0 = q.x * k0.x + q.y * k0.y;
            float p1 = q.x * k1.x + q.y * k1.y;
            float p2 = q.x * k2.x + q.y * k2.y;
            float p3 = q.x * k3.x + q.y * k3.y;
            p0 += __shfl_xor(p0, 1, 64);
            p1 += __shfl_xor(p1, 1, 64);
            p2 += __shfl_xor(p2, 1, 64);
            p3 += __shfl_xor(p3, 1, 64);
            p0 += __shfl_xor(p0, 2, 64);
            p1 += __shfl_xor(p1, 2, 64);
            p2 += __shfl_xor(p2, 2, 64);
            p3 += __shfl_xor(p3, 2, 64);
            p0 += __shfl_xor(p0, 4, 64);
            p1 += __shfl_xor(p1, 4, 64);
            p2 += __shfl_xor(p2, 4, 64);
            p3 += __shfl_xor(p3, 4, 64);
            float w0 = __expf(fminf(fmaxf(p0 * 0.25f, -5.f), 5.f));
            float w1 = __expf(fminf(fmaxf(p1 * 0.25f, -5.f), 5.f));
            float w2 = __expf(fminf(fmaxf(p2 * 0.25f, -5.f), 5.f));
            float w3 = __expf(fminf(fmaxf(p3 * 0.25f, -5.f), 5.f));
            s += w0 + w1 + w2 + w3;
            ax += w0 * v0.x + w1 * v1.x + w2 * v2.x + w3 * v3.x;
            ay += w0 * v0.y + w1 * v1.y + w2 * v2.y + w3 * v3.y;
        }
        for (; e < rem; e++) {
            int j = __shfl(myj, e, 64);
            float2 k = ld2b(Kb + (size_t)j * 128 + lane * 2);
            float2 v = ld2b(Vb + (size_t)j * 128 + lane * 2);
            float p = q.x * k.x + q.y * k.y;
            p += __shfl_xor(p, 1, 64);
            p += __shfl_xor(p, 2, 64);
            p += __shfl_xor(p, 4, 64);
            float w = __expf(fminf(fmaxf(p * 0.25f, -5.f), 5.f));
            s += w;
            ax += w * v.x;
            ay += w * v.y;
        }
    }
    float inv = 1.0f / (s + 1e-16f);
    unsigned o = pack2(ax * inv, ay * inv);
    *(unsigned*)(agg + (size_t)i * 128 + lane * 2) = o;
}

// ---------- WO projection + residual + BN1 stats, coalesced ----------
__global__ __launch_bounds__(256) void wo_k(const unsigned short* __restrict__ agg,
                                            const unsigned short* __restrict__ WOt,
                                            const float* __restrict__ x,
                                            const float* __restrict__ bO,
                                            unsigned short* __restrict__ Yb,
                                            float* __restrict__ cs1, float* __restrict__ cq1) {
    __shared__ unsigned short As[64][136];
    __shared__ unsigned short Bs[128][136];
    const int tid = threadIdx.x;
    const int lane = tid & 63, wave = tid >> 6;
    const int quad = lane >> 4, l15 = lane & 15;
    const int wr = wave >> 1, wc = wave & 1;
    const int row0 = blockIdx.x * 64;

#pragma unroll
    for (int j = 0; j < 4; j++) {
        int idx = tid + j * 256;
        int u = idx >> 4, k8 = (idx & 15) * 8;
        int grow = row0 + u;
        uint4 val = {0u, 0u, 0u, 0u};
        if (grow < N) val = *(const uint4*)(agg + (size_t)grow * 128 + k8);
        *(uint4*)&As[u][k8] = val;
    }
#pragma unroll
    for (int it = 0; it < 8; it++) {
        int c = tid + it * 256;
        int n = c >> 4, k8 = (c & 15) * 8;
        *(uint4*)&Bs[n][k8] = *(const uint4*)(WOt + (size_t)n * 128 + k8);
    }
    __syncthreads();

    f32x4 acc[2][4];
#pragma unroll
    for (int i = 0; i < 2; i++)
#pragma unroll
        for (int j = 0; j < 4; j++) acc[i][j] = (f32x4){0.f, 0.f, 0.f, 0.f};
#pragma unroll
    for (int ks = 0; ks < 4; ks++) {
        int k0 = ks * 32 + quad * 8;
        bfrag8 a0 = *(const bfrag8*)&As[wr * 32 + l15][k0];
        bfrag8 a1 = *(const bfrag8*)&As[wr * 32 + 16 + l15][k0];
#pragma unroll
        for (int jn = 0; jn < 4; jn++) {
            bfrag8 b = *(const bfrag8*)&Bs[wc * 64 + jn * 16 + l15][k0];
            acc[0][jn] = __builtin_amdgcn_mfma_f32_16x16x32_bf16(a0, b, acc[0][jn], 0, 0, 0);
            acc[1][jn] = __builtin_amdgcn_mfma_f32_16x16x32_bf16(a1, b, acc[1][jn], 0, 0, 0);
        }
    }
    __syncthreads();

    // stage residual x tile coalesced over Bs; stats scratch lives above Xs
    float* Xf = (float*)&Bs[0][0];  // [64][132]
    float* smf = Xf + 64 * 132;     // 256 floats (fits: 34816-33792=1024B)
    if (tid < 256) smf[tid] = 0.f;
#pragma unroll
    for (int j = 0; j < 8; j++) {
        int idx = tid + j * 256;
        int u = idx >> 5, c4 = (idx & 31) * 4;
        int grow = row0 + u;
        float4 v = {0.f, 0.f, 0.f, 0.f};
        if (grow < N) v = *(const float4*)(x + (size_t)grow * 128 + c4);
        *(float4*)(Xf + u * 132 + c4) = v;
    }
    __syncthreads();

    unsigned short(*Cs)[136] = (unsigned short(*)[136]) & As[0][0];
    float colS[4] = {0.f, 0.f, 0.f, 0.f}, colQ[4] = {0.f, 0.f, 0.f, 0.f};
#pragma unroll
    for (int i = 0; i < 2; i++) {
        int rb = wr * 32 + i * 16 + quad * 4;
#pragma unroll
        for (int jn = 0; jn < 4; jn++) {
            int cl = wc * 64 + jn * 16 + l15;
            float bv = bO[cl];
#pragma unroll
            for (int r = 0; r < 4; r++) {
                int rl = rb + r;
                float v = acc[i][jn][r] + bv + Xf[rl * 132 + cl];
                Cs[rl][cl] = f2b(v);
                if (row0 + rl < N) {
                    colS[jn] += v;
                    colQ[jn] += v * v;
                }
            }
        }
    }
    __syncthreads();
#pragma unroll
    for (int jn = 0; jn < 4; jn++) {
        float s = colS[jn], q = colQ[jn];
        s += __shfl_xor(s, 16, 64);
        q += __shfl_xor(q, 16, 64);
        s += __shfl_xor(s, 32, 64);
        q += __shfl_xor(q, 32, 64);
        if (quad == 0) {
            int cl = wc * 64 + jn * 16 + l15;
            atomicAdd(&smf[cl], s);
            atomicAdd(&smf[128 + cl], q);
        }
    }
    __syncthreads();
    if (tid < 128)
        atomicAdd(&cs1[tid], smf[tid]);
    else
        atomicAdd(&cq1[tid - 128], smf[tid]);
#pragma unroll
    for (int j = 0; j < 4; j++) {
        int idx = tid + j * 256;
        int u = idx >> 4, col8 = (idx & 15) * 8;
        int grow = row0 + u;
        if (grow < N) *(uint4*)(Yb + (size_t)grow * 128 + col8) = *(const uint4*)&Cs[u][col8];
    }
}

// ---------- BN1 finalize + folded FFN bias b1' ----------
__global__ void bnfin1x(const float* __restrict__ sum, const float* __restrict__ sq,
                        const float* __restrict__ g, const float* __restrict__ be,
                        const float* __restrict__ W1, const float* __restrict__ b1,
                        float* __restrict__ ss, float* __restrict__ b1p) {
    __shared__ float sh[128];
    int t = threadIdx.x;
    if (t < 128) {
        float mu = sum[t] * (1.f / N);
        float var = sq[t] * (1.f / N) - mu * mu;
        float sc = g[t] * rsqrtf(var + 1e-5f);
        float shft = be[t] - mu * sc;
        ss[t] = sc;
        ss[128 + t] = shft;
        sh[t] = shft;
    }
    __syncthreads();
    float acc = b1[t];
#pragma unroll 4
    for (int k = 0; k < 128; k++) acc += sh[k] * W1[k * 256 + t];
    b1p[t] = acc;
}

// ---------- scale W1 by BN1 scale (folded) ----------
__global__ void scalew1_k(const float* __restrict__ W1tf, const float* __restrict__ ss,
                          unsigned short* __restrict__ W1s) {
    int i = blockIdx.x * 256 + threadIdx.x;  // 32768
    W1s[i] = f2b(W1tf[i] * ss[i & 127]);
}

// ---------- fused FFN: T = relu(Y'@W1'+b1')@W2 + b2 + Y' ; Z in LDS ----------
__global__ __launch_bounds__(256) void ffn_k(const unsigned short* __restrict__ Yb,
                                             const unsigned short* __restrict__ W1s,
                                             const unsigned short* __restrict__ W2t,
                                             const float* __restrict__ ss1,
                                             const float* __restrict__ b1p,
                                             const float* __restrict__ b2,
                                             unsigned short* __restrict__ Tb,
                                             float* __restrict__ cs2, float* __restrict__ cq2) {
    __shared__ unsigned short As[64][136];   // Y tile (bf16), kept for residual
    __shared__ unsigned short Zs[64][264];   // Z tile (bf16); reused as T bounce
    __shared__ float Cf[640];                // ss1(256) | b1p(256) | b2(128); reused for stats
    const int tid = threadIdx.x;
    const int lane = tid & 63, wave = tid >> 6;
    const int quad = lane >> 4, l15 = lane & 15;
    const int wr = wave >> 1, wc = wave & 1;
    const int row0 = blockIdx.x * 64;

    Cf[tid] = ss1[tid];
    Cf[256 + tid] = b1p[tid];
    if (tid < 128) Cf[512 + tid] = b2[tid];
#pragma unroll
    for (int j = 0; j < 4; j++) {
        int idx = tid + j * 256;
        int u = idx >> 4, k8 = (idx & 15) * 8;
        int grow = row0 + u;
        uint4 val = {0u, 0u, 0u, 0u};
        if (grow < N) val = *(const uint4*)(Yb + (size_t)grow * 128 + k8);
        *(uint4*)&As[u][k8] = val;
    }
    __syncthreads();

    // gemm1: Z = relu(Y @ W1' + b1'), B-frags direct from global (L2-hot)
#pragma unroll
    for (int h = 0; h < 2; h++) {
        f32x4 acc[2][4];
#pragma unroll
        for (int i = 0; i < 2; i++)
#pragma unroll
            for (int j = 0; j < 4; j++) acc[i][j] = (f32x4){0.f, 0.f, 0.f, 0.f};
#pragma unroll
        for (int ks = 0; ks < 4; ks++) {
            int k0 = ks * 32 + quad * 8;
            bfrag8 a0 = *(const bfrag8*)&As[wr * 32 + l15][k0];
            bfrag8 a1 = *(const bfrag8*)&As[wr * 32 + 16 + l15][k0];
#pragma unroll
            for (int jn = 0; jn < 4; jn++) {
                int n = h * 128 + wc * 64 + jn * 16 + l15;
                bfrag8 b = *(const bfrag8*)(W1s + (size_t)n * 128 + k0);
                acc[0][jn] = __builtin_amdgcn_mfma_f32_16x16x32_bf16(a0, b, acc[0][jn], 0, 0, 0);
                acc[1][jn] = __builtin_amdgcn_mfma_f32_16x16x32_bf16(a1, b, acc[1][jn], 0, 0, 0);
            }
        }
#pragma unroll
        for (int i = 0; i < 2; i++) {
            int rb = wr * 32 + i * 16 + quad * 4;
#pragma unroll
            for (int jn = 0; jn < 4; jn++) {
                int gc = h * 128 + wc * 64 + jn * 16 + l15;
                float bv = Cf[256 + gc];
#pragma unroll
                for (int r = 0; r < 4; r++)
                    Zs[rb + r][gc] = f2b(fmaxf(acc[i][jn][r] + bv, 0.f));
            }
        }
    }
    __syncthreads();  // Z complete (cross-wave cols)

    // gemm2: T = Z @ W2 + b2 + BN1(Y)
    f32x4 acc2[2][4];
#pragma unroll
    for (int i = 0; i < 2; i++)
#pragma unroll
        for (int j = 0; j < 4; j++) acc2[i][j] = (f32x4){0.f, 0.f, 0.f, 0.f};
#pragma unroll
    for (int ks = 0; ks < 8; ks++) {
        int k0 = ks * 32 + quad * 8;
        bfrag8 a0 = *(const bfrag8*)&Zs[wr * 32 + l15][k0];
        bfrag8 a1 = *(const bfrag8*)&Zs[wr * 32 + 16 + l15][k0];
#pragma unroll
        for (int jn = 0; jn < 4; jn++) {
            int n = wc * 64 + jn * 16 + l15;
            bfrag8 b = *(const bfrag8*)(W2t + (size_t)n * 256 + k0);
            acc2[0][jn] = __builtin_amdgcn_mfma_f32_16x16x32_bf16(a0, b, acc2[0][jn], 0, 0, 0);
            acc2[1][jn] = __builtin_amdgcn_mfma_f32_16x16x32_bf16(a1, b, acc2[1][jn], 0, 0, 0);
        }
    }
    __syncthreads();  // Zs reads done -> reuse as T bounce

    unsigned short(*Ts)[136] = (unsigned short(*)[136]) & Zs[0][0];
    float colS[4] = {0.f, 0.f, 0.f, 0.f}, colQ[4] = {0.f, 0.f, 0.f, 0.f};
#pragma unroll
    for (int i = 0; i < 2; i++) {
        int rb = wr * 32 + i * 16 + quad * 4;
#pragma unroll
        for (int jn = 0; jn < 4; jn++) {
            int cl = wc * 64 + jn * 16 + l15;
            float s1v = Cf[cl], sh1v = Cf[128 + cl], b2v = Cf[512 + cl];
#pragma unroll
            for (int r = 0; r < 4; r++) {
                int rl = rb + r;
                float yv = b2f(As[rl][cl]);
                float v = acc2[i][jn][r] + b2v + yv * s1v + sh1v;
                Ts[rl][cl] = f2b(v);
                if (row0 + rl < N) {
                    colS[jn] += v;
                    colQ[jn] += v * v;
                }
            }
        }
    }
    __syncthreads();  // Ts complete; Cf free

    Cf[tid] = 0.f;
    __syncthreads();
#pragma unroll
    for (int jn = 0; jn < 4; jn++) {
        float s = colS[jn], q = colQ[jn];
        s += __shfl_xor(s, 16, 64);
        q += __shfl_xor(q, 16, 64);
        s += __shfl_xor(s, 32, 64);
        q += __shfl_xor(q, 32, 64);
        if (quad == 0) {
            int cl = wc * 64 + jn * 16 + l15;
            atomicAdd(&Cf[cl], s);
            atomicAdd(&Cf[128 + cl], q);
        }
    }
    __syncthreads();
    if (tid < 128)
        atomicAdd(&cs2[tid], Cf[tid]);
    else
        atomicAdd(&cq2[tid - 128], Cf[tid]);
#pragma unroll
    for (int j = 0; j < 4; j++) {
        int idx = tid + j * 256;
        int u = idx >> 4, col8 = (idx & 15) * 8;
        int grow = row0 + u;
        if (grow < N) *(uint4*)(Tb + (size_t)grow * 128 + col8) = *(const uint4*)&Ts[u][col8];
    }
}

__global__ void bnfin_k(const float* __restrict__ sum, const float* __restrict__ sq,
                        const float* __restrict__ g, const float* __restrict__ be,
                        float* __restrict__ ss) {
    int c = threadIdx.x;
    float mu = sum[c] * (1.f / N);
    float var = sq[c] * (1.f / N) - mu * mu;
    float sc = g[c] * rsqrtf(var + 1e-5f);
    ss[c] = sc;
    ss[128 + c] = be[c] - mu * sc;
}

__global__ void bnout_k(const unsigned short* __restrict__ T, const float* __restrict__ ss,
                        float* __restrict__ Out) {
    size_t idx = ((size_t)blockIdx.x * 256 + threadIdx.x) * 8;
    if (idx >= (size_t)N * 128) return;
    int c0 = (int)(idx & 127);
    uint4 tv = *(const uint4*)(T + idx);
    float f[8];
    f[0] = __uint_as_float(tv.x << 16);
    f[1] = __uint_as_float(tv.x & 0xFFFF0000u);
    f[2] = __uint_as_float(tv.y << 16);
    f[3] = __uint_as_float(tv.y & 0xFFFF0000u);
    f[4] = __uint_as_float(tv.z << 16);
    f[5] = __uint_as_float(tv.z & 0xFFFF0000u);
    f[6] = __uint_as_float(tv.w << 16);
    f[7] = __uint_as_float(tv.w & 0xFFFF0000u);
    float4 o0, o1;
    o0.x = f[0] * ss[c0 + 0] + ss[128 + c0 + 0];
    o0.y = f[1] * ss[c0 + 1] + ss[128 + c0 + 1];
    o0.z = f[2] * ss[c0 + 2] + ss[128 + c0 + 2];
    o0.w = f[3] * ss[c0 + 3] + ss[128 + c0 + 3];
    o1.x = f[4] * ss[c0 + 4] + ss[128 + c0 + 4];
    o1.y = f[5] * ss[c0 + 5] + ss[128 + c0 + 5];
    o1.z = f[6] * ss[c0 + 6] + ss[128 + c0 + 6];
    o1.w = f[7] * ss[c0 + 7] + ss[128 + c0 + 7];
    *(float4*)(Out + idx) = o0;
    *(float4*)(Out + idx + 4) = o1;
}

extern "C" void kernel_launch(void* const* d_in, const int* in_sizes, int n_in,
                              void* d_out, int out_size, void* d_ws, size_t ws_size,
                              hipStream_t stream) {
    const float* x = (const float*)d_in[0];
    const int* eidx = (const int*)d_in[1];
    const float* WQ = (const float*)d_in[2];
    const float* WK = (const float*)d_in[3];
    const float* WV = (const float*)d_in[4];
    const float* WO = (const float*)d_in[5];
    const float* bO = (const float*)d_in[6];
    const float* W1 = (const float*)d_in[7];
    const float* b1 = (const float*)d_in[8];
    const float* W2 = (const float*)d_in[9];
    const float* b2 = (const float*)d_in[10];
    const float* g1 = (const float*)d_in[11];
    const float* be1 = (const float*)d_in[12];
    const float* g2 = (const float*)d_in[13];
    const float* be2 = (const float*)d_in[14];
    float* out = (float*)d_out;

    char* ws = (char*)d_ws;
    int* counts = (int*)(ws + OFF_COUNTS);
    int* cursors = (int*)(ws + OFF_CURSORS);
    float* cs1 = (float*)(ws + OFF_CS1);
    float* cq1 = (float*)(ws + OFF_CQ1);
    float* cs2 = (float*)(ws + OFF_CS2);
    float* cq2 = (float*)(ws + OFF_CQ2);
    int* offs = (int*)(ws + OFF_OFFS);
    int* bsum = (int*)(ws + OFF_BSUM);
    int* bpref = (int*)(ws + OFF_BPREF);
    float* ss1 = (float*)(ws + OFF_SS1);
    float* ss2 = (float*)(ws + OFF_SS2);
    float* b1p = (float*)(ws + OFF_B1P);
    int* csr = (int*)(ws + OFF_CSR);
    unsigned short* WtQKV = (unsigned short*)(ws + OFF_WTQKV);
    unsigned short* WOt = (unsigned short*)(ws + OFF_WOT);
    float* W1tf = (float*)(ws + OFF_W1TF);
    unsigned short* W1s = (unsigned short*)(ws + OFF_W1S);
    unsigned short* W2t = (unsigned short*)(ws + OFF_W2T);
    unsigned short* qkv = (unsigned short*)(ws + OFF_QKV);
    unsigned short* agg = (unsigned short*)(ws + OFF_AGG);
    unsigned short* Yb = (unsigned short*)(ws + OFF_Y);
    unsigned short* Tb = (unsigned short*)(ws + OFF_T);

    hipMemsetAsync(ws, 0, ZERO_END, stream);
    prep_w<<<512, 256, 0, stream>>>(WQ, WK, WV, WO, W1, W2, WtQKV, WOt, W1tf, W2t);

    const int EB = (E + 255) / 256;
    hist_k<<<EB, 256, 0, stream>>>(eidx, counts);
    scan_a<<<196, 256, 0, stream>>>(counts, offs, bsum);
    scan_b<<<1, 256, 0, stream>>>(bsum, bpref);
    scan_c<<<196, 256, 0, stream>>>(offs, bpref);
    fill_k<<<EB, 256, 0, stream>>>(eidx, offs, cursors, csr);

    const int MB = (N + 63) / 64;  // 782
    qkv_k<<<MB, 256, 0, stream>>>(x, WtQKV, qkv);
    attn_k<<<(N + 3) / 4, 256, 0, stream>>>(qkv, csr, offs, counts, agg);
    wo_k<<<MB, 256, 0, stream>>>(agg, WOt, x, bO, Yb, cs1, cq1);
    bnfin1x<<<1, 256, 0, stream>>>(cs1, cq1, g1, be1, W1, b1, ss1, b1p);
    scalew1_k<<<128, 256, 0, stream>>>(W1tf, ss1, W1s);
    ffn_k<<<MB, 256, 0, stream>>>(Yb, W1s, W2t, ss1, b1p, b2, Tb, cs2, cq2);
    bnfin_k<<<1, 128, 0, stream>>>(cs2, cq2, g2, be2, ss2);
    bnout_k<<<(int)(((size_t)N * 128 / 8 + 255) / 256), 256, 0, stream>>>(Tb, ss2, out);
}